// Round 3
// baseline (153.568 us; speedup 1.0000x reference)
//
#include <hip/hip_runtime.h>
#include <stdint.h>
#include <math.h>

// Problem constants (fixed by the reference's setup_inputs)
#define N_BATCH 8
#define A_ELEMS 500000          // anchors per batch
#define TOPK    2000
#define NBINS   2048            // fallback histogram bins
#define CAP     4096            // candidate capacity per batch (expected ~3475 +- 59)
#define BCAP2   128             // per-scan-block private candidate cap (expected ~27 +- 5)
#define SBLK    128             // scan blocks per batch
#define FBCAP   8192            // fallback candidate capacity (fits in priv region)
#define NB2     2048            // counting-sort bins
#define SHIFT2  13              // sortable>>13 -> ~1300 live bins for scores in [2.46, ~6)
#define BBOX_CLIP 4.135166556742356f  // log(1000/16)

// Session model (measured r0-r2): harness floor ~126 us, ~5.5 us per dependent
// launch, kernel work ~13 us. Round 1 proved device-scope __threadfence()
// tickets cost ~90+ us (L2 wb/inv storms on non-coherent XCD L2s) — so all
// fusion here stays fence-free: the rank+decode merge is enabled by replacing
// the O(cnt^2) all-pairs rank (needed 64 blocks/batch) with an LDS counting
// sort by score high-bits (one block/batch, O(cnt * binsize) exact ranks).

// Monotone map float -> uint32 (ascending). Larger u <=> larger float.
__device__ __forceinline__ uint32_t f2sortable(float f) {
    uint32_t b = __float_as_uint(f);
    return (b & 0x80000000u) ? ~b : (b | 0x80000000u);
}

// Gather the g-th candidate (block-major compacted order) from the private
// per-scan-block lists, given the exclusive prefix table pre[0..SBLK] in LDS.
__device__ __forceinline__ unsigned long long gather_key(
    const unsigned long long* pvb, const uint32_t* pre, uint32_t g) {
    int lo = 0, hi = SBLK - 1;   // largest b with pre[b] <= g
    while (lo < hi) { int mid = (lo + hi + 1) >> 1; if (pre[mid] <= g) lo = mid; else hi = mid - 1; }
    return pvb[(size_t)lo * BCAP2 + (g - pre[lo])];
}

// Decode one candidate and write output row `rank` (shared by hot + fallback).
__device__ __forceinline__ void decode_write(
    const float* anchors, const float* breg, int n,
    unsigned long long key, uint32_t rank, float* out) {
    const uint32_t u    = (uint32_t)(key >> 32);
    const uint32_t idx  = ~((uint32_t)key);
    const uint32_t bits = (u & 0x80000000u) ? (u ^ 0x80000000u) : ~u;
    const float score = __uint_as_float(bits);
    const float4 a = ((const float4*)anchors)[(size_t)n * A_ELEMS + idx];
    const float4 b = ((const float4*)breg)[(size_t)n * A_ELEMS + idx];
    float w  = a.z - a.x + 1.0f;
    float h  = a.w - a.y + 1.0f;
    float cx = a.x + 0.5f * w;
    float cy = a.y + 0.5f * h;
    float dw = fminf(b.z, BBOX_CLIP);
    float dh = fminf(b.w, BBOX_CLIP);
    float pcx = b.x * w + cx;
    float pcy = b.y * h + cy;
    float pw  = expf(dw) * w;
    float ph  = expf(dh) * h;
    float* row = out + ((size_t)n * TOPK + rank) * 5;
    row[0] = pcx - 0.5f * pw;
    row[1] = pcy - 0.5f * ph;
    row[2] = pcx + 0.5f * pw - 1.0f;
    row[3] = pcy + 0.5f * ph - 1.0f;
    row[4] = score;
}

// ---------------- pass 1: speculative threshold compact (unchanged, proven) ------
// Static threshold T = 2.46: per-batch count above it is ~3475 +- 59 for
// N(0,1) scores — inside [TOPK, CAP] by >10 sigma on both sides. Pure
// streaming read; candidates staged via one LDS counter into a PRIVATE
// per-block list. key = (sortable<<32)|~idx: key desc == score desc, index
// asc (exact jax.lax.top_k order; keys unique).
__global__ __launch_bounds__(256) void scan_kernel(const float* __restrict__ obj,
                                                   uint32_t* __restrict__ bcount,
                                                   unsigned long long* __restrict__ priv) {
    __shared__ uint32_t lcount;
    const int n = blockIdx.y, blk = blockIdx.x;
    const int tid = (int)threadIdx.x;
    if (tid == 0) lcount = 0;
    __syncthreads();
    const float Tf = 2.46f;                    // float-domain compare (no NaNs in input)
    const float4* o4 = (const float4*)(obj + (size_t)n * A_ELEMS);
    unsigned long long* pv = priv + ((size_t)n * SBLK + blk) * BCAP2;
    const int n4 = A_ELEMS / 4;  // 125000, exact
    for (int i = blk * 256 + tid; i < n4; i += SBLK * 256) {
        float4 v = o4[i];
        float fs[4] = {v.x, v.y, v.z, v.w};
        #pragma unroll
        for (int c = 0; c < 4; ++c) {
            if (fs[c] >= Tf) {
                uint32_t pos = atomicAdd(&lcount, 1u);     // LDS atomic — rare (~0.07%)
                if (pos < BCAP2) {
                    uint32_t idx = (uint32_t)(i * 4 + c);
                    pv[pos] = ((unsigned long long)f2sortable(fs[c]) << 32) |
                              (unsigned long long)(~idx);
                }
            }
        }
    }
    __syncthreads();
    if (tid == 0) bcount[(size_t)n * SBLK + blk] = lcount;   // uncapped (overflow check)
}

// ---------------- pass 2: counting-sort rank + decode (one block per batch) ------
// rbin = (NB2-1) - clamp((sortable>>13) - BASE): ascending rbin == descending
// score. Exact position = excl_prefix[rbin] + #{same-bin keys > mine}
// (keys unique -> positions unique & exact). Hot-bin size ~40 near the 2.46
// threshold, decaying fast -> per-key tie-break cost is tiny.
__global__ __launch_bounds__(1024) void sortdecode_kernel(
    const float* __restrict__ anchors, const float* __restrict__ breg,
    const float* __restrict__ obj,
    const uint32_t* __restrict__ bcount,
    unsigned long long* __restrict__ priv,      // non-const: fallback reuses it
    float* __restrict__ out) {
    __shared__ uint32_t cs[SBLK], ps[SBLK], pre[SBLK + 1];
    __shared__ uint32_t bad;
    __shared__ uint32_t hist[NB2];              // bin sizes (also fallback histogram)
    __shared__ uint32_t boff[NB2];              // exclusive prefix by rbin
    __shared__ uint32_t bcur[NB2];              // placement cursors
    __shared__ uint32_t ws2[1024];              // scan scratch
    __shared__ unsigned long long s[CAP];       // 32 KB staging, sorted by bin
    __shared__ uint32_t lcnt, cutb;
    const int n = blockIdx.x;
    const int tid = (int)threadIdx.x;

    // ---- prefix over the 128 per-scan-block counts ----
    if (tid == 0) bad = 0;
    __syncthreads();
    if (tid < SBLK) {
        uint32_t c = bcount[(size_t)n * SBLK + tid];
        cs[tid] = c; ps[tid] = c;
        if (c > BCAP2) atomicOr(&bad, 1u);
    }
    __syncthreads();
    for (int off = 1; off < SBLK; off <<= 1) {
        uint32_t v = 0;
        if (tid < SBLK) { v = ps[tid]; if (tid >= off) v += ps[tid - off]; }
        __syncthreads();
        if (tid < SBLK) ps[tid] = v;
        __syncthreads();
    }
    const uint32_t total = (tid < SBLK) ? 0u : 0u;  // (value read below from ps)
    __syncthreads();
    const uint32_t cnt_all = ps[SBLK - 1];
    if (tid < SBLK) pre[tid] = ps[tid] - cs[tid];
    if (tid == 0) pre[SBLK] = cnt_all;
    __syncthreads();
    const bool okl = (bad == 0) && (cnt_all >= TOPK) && (cnt_all <= CAP);

    if (okl) {
        const uint32_t cnt = cnt_all;
        // ---- zero bins ----
        for (int i = tid; i < NB2; i += 1024) hist[i] = 0;
        __syncthreads();
        // ---- gather keys (<=4 per thread) + histogram ----
        const unsigned long long* pvb = priv + (size_t)n * SBLK * BCAP2;
        const uint32_t BASE = f2sortable(2.46f) >> SHIFT2;   // folds to constant
        unsigned long long kk[4];
        uint32_t kb[4];
        #pragma unroll
        for (int i = 0; i < 4; ++i) {
            const uint32_t g = (uint32_t)tid + (uint32_t)i * 1024u;
            kb[i] = 0xFFFFFFFFu;
            if (g < cnt) {
                unsigned long long k = gather_key(pvb, pre, g);
                uint32_t d = ((uint32_t)(k >> 32) >> SHIFT2) - BASE;
                if (d > (NB2 - 1)) d = NB2 - 1;
                const uint32_t rbin = (NB2 - 1) - d;        // ascending = score desc
                kk[i] = k; kb[i] = rbin;
                atomicAdd(&hist[rbin], 1u);
            }
        }
        __syncthreads();
        // ---- exclusive prefix over 2048 bins (2 bins/thread + 1024-scan) ----
        const uint32_t h0 = hist[2 * tid], h1 = hist[2 * tid + 1];
        const uint32_t sum2 = h0 + h1;
        ws2[tid] = sum2;
        __syncthreads();
        for (int off = 1; off < 1024; off <<= 1) {
            uint32_t v = ws2[tid];
            uint32_t w = (tid >= off) ? ws2[tid - off] : 0u;
            __syncthreads();
            ws2[tid] = v + w;
            __syncthreads();
        }
        const uint32_t base2 = ws2[tid] - sum2;             // exclusive of my pair
        boff[2 * tid]     = base2;
        bcur[2 * tid]     = base2;
        boff[2 * tid + 1] = base2 + h0;
        bcur[2 * tid + 1] = base2 + h0;
        __syncthreads();
        // ---- placement into bin-sorted staging ----
        #pragma unroll
        for (int i = 0; i < 4; ++i) {
            if (kb[i] != 0xFFFFFFFFu) {
                uint32_t slot = atomicAdd(&bcur[kb[i]], 1u);
                s[slot] = kk[i];
            }
        }
        __syncthreads();
        // ---- exact within-bin rank + decode + write ----
        #pragma unroll
        for (int i = 0; i < 4; ++i) {
            if (kb[i] == 0xFFFFFFFFu) continue;
            const uint32_t lo = boff[kb[i]];
            const uint32_t sz = hist[kb[i]];
            const unsigned long long mk = kk[i];
            uint32_t r = 0;
            for (uint32_t j = lo; j < lo + sz; ++j) r += (s[j] > mk);
            const uint32_t pos = lo + r;                    // exact descending rank
            if (pos < TOPK)
                decode_write(anchors, breg, n, mk, pos, out);
        }
        return;
    }

    // ---- exact fallback: never taken for the fixed input seed (>10 sigma) ----
    for (int i = tid; i < NBINS; i += 1024) hist[i] = 0;
    if (tid == 0) lcnt = 0;
    __syncthreads();
    const float* o = obj + (size_t)n * A_ELEMS;
    for (int i = tid; i < A_ELEMS; i += 1024)
        atomicAdd(&hist[f2sortable(o[i]) >> 21], 1u);
    __syncthreads();
    if (tid == 0) {
        uint32_t cum = 0; int b;
        for (b = NBINS - 1; b > 0; --b) { cum += hist[b]; if (cum >= TOPK) break; }
        cutb = (uint32_t)b;
    }
    __syncthreads();
    const uint32_t cb = cutb;
    unsigned long long* fbn = priv + (size_t)n * SBLK * BCAP2;  // 16384 slots, reuse
    for (int i = tid; i < A_ELEMS; i += 1024) {
        uint32_t u = f2sortable(o[i]);
        if ((u >> 21) >= cb) {
            uint32_t pos = atomicAdd(&lcnt, 1u);
            if (pos < FBCAP)
                fbn[pos] = ((unsigned long long)u << 32) | (unsigned long long)(~(uint32_t)i);
        }
    }
    __syncthreads();
    const uint32_t cnt2 = lcnt < FBCAP ? lcnt : FBCAP;
    for (uint32_t t = tid; t < cnt2; t += 1024) {           // brute force; correct, cold
        const unsigned long long myk = fbn[t];
        uint32_t rank = 0;
        for (uint32_t j = 0; j < cnt2; ++j) rank += (fbn[j] > myk);
        if (rank < TOPK)
            decode_write(anchors, breg, n, myk, rank, out);
    }
}

extern "C" void kernel_launch(void* const* d_in, const int* in_sizes, int n_in,
                              void* d_out, int out_size, void* d_ws, size_t ws_size,
                              hipStream_t stream) {
    const float* anchors    = (const float*)d_in[0];  // [8,500000,4]
    const float* objectness = (const float*)d_in[1];  // [8,500000,1]
    const float* breg       = (const float*)d_in[2];  // [8,500000,4]
    float* out = (float*)d_out;                        // [8,2000,5]

    // Workspace layout (every region written-before-read each call):
    //   [0,    4096)     bcount  uint32[8][128]
    //   [4096, 1052672)  priv    uint64[8][128][128]   (also fallback area)
    uint8_t* ws = (uint8_t*)d_ws;
    uint32_t* bcount         = (uint32_t*)ws;
    unsigned long long* priv = (unsigned long long*)(ws + 4096);

    dim3 g1(SBLK, N_BATCH);
    scan_kernel<<<g1, 256, 0, stream>>>(objectness, bcount, priv);
    sortdecode_kernel<<<N_BATCH, 1024, 0, stream>>>(anchors, breg, objectness,
                                                    bcount, priv, out);
}

// Round 4
// 149.243 us; speedup vs baseline: 1.0290x; 1.0290x over previous
//
#include <hip/hip_runtime.h>
#include <stdint.h>
#include <math.h>

// Problem constants (fixed by the reference's setup_inputs)
#define N_BATCH 8
#define A_ELEMS 500000          // anchors per batch
#define TOPK    2000
#define NBINS   2048            // 11-bit histogram (exact-fallback path only)
#define CAP     4096            // candidate capacity per batch (expected ~3475 +- 59)
#define BCAP2   128             // per-scan-block private candidate cap (expected ~27 +- 5)
#define SBLK    128             // scan blocks per batch
#define SEG     16              // key segments for rank phase (SEG*SEGK = CAP)
#define SEGK    256             // keys per segment
#define GRP     4               // candidate groups of 1024 per batch (GRP*1024 = CAP)
#define FBCAP   8192            // fallback candidate capacity (fits in priv region)
#define BBOX_CLIP 4.135166556742356f  // log(1000/16)

// Session ledger (measured):
//   r0 5-kernel: 160.8 | r1 fused+fences: 288.1 | r2 3-kernel: 149.8 (BEST)
//   r3 2-kernel counting-sort: 153.6
// Lessons: (1) device-scope __threadfence tickets cost ~90 us (L2 wb/inv
// storms on non-coherent XCD L2s) — never fuse across grid-wide deps with
// fences here. (2) Fusing by concentrating work (8-block counting sort) trades
// a 5.5 us launch for ~9 us of lost parallelism (barrier chains + scattered-
// load latency on 8 of 256 CUs) — also a loss. 3 well-shaped fence-free
// kernels is the measured optimum; this file is the r2 structure restored.

// Monotone map float -> uint32 (ascending). Larger u <=> larger float.
__device__ __forceinline__ uint32_t f2sortable(float f) {
    uint32_t b = __float_as_uint(f);
    return (b & 0x80000000u) ? ~b : (b | 0x80000000u);
}

// Gather the g-th candidate (in block-major compacted order) from the private
// per-scan-block lists, given the exclusive prefix table pre[0..SBLK].
__device__ __forceinline__ unsigned long long gather_key(
    const unsigned long long* pvb, const uint32_t* pre, uint32_t g) {
    int lo = 0, hi = SBLK - 1;   // largest b with pre[b] <= g
    while (lo < hi) { int mid = (lo + hi + 1) >> 1; if (pre[mid] <= g) lo = mid; else hi = mid - 1; }
    return pvb[(size_t)lo * BCAP2 + (g - pre[lo])];
}

// ---------------- pass 1: speculative threshold compact (hot path) ----------------
// Static threshold T = 2.46: for N(0,1) scores the per-batch count above it is
// ~3475 +- 59 — inside [TOPK, CAP] by >10 sigma on both sides. Pure streaming
// read; candidates staged via one LDS counter into a PRIVATE per-block list
// (no global atomics, no fences, no pre-zero). key = (sortable<<32)|~idx:
// key desc == score desc, index asc (exact jax.lax.top_k order; keys unique).
__global__ __launch_bounds__(256) void scan_kernel(const float* __restrict__ obj,
                                                   uint32_t* __restrict__ bcount,
                                                   unsigned long long* __restrict__ priv) {
    __shared__ uint32_t lcount;
    const int n = blockIdx.y, blk = blockIdx.x;
    const int tid = (int)threadIdx.x;
    if (tid == 0) lcount = 0;
    __syncthreads();
    const float Tf = 2.46f;                    // float-domain compare (no NaNs in input)
    const float4* o4 = (const float4*)(obj + (size_t)n * A_ELEMS);
    unsigned long long* pv = priv + ((size_t)n * SBLK + blk) * BCAP2;
    const int n4 = A_ELEMS / 4;  // 125000, exact
    for (int i = blk * 256 + tid; i < n4; i += SBLK * 256) {
        float4 v = o4[i];
        float fs[4] = {v.x, v.y, v.z, v.w};
        #pragma unroll
        for (int c = 0; c < 4; ++c) {
            if (fs[c] >= Tf) {
                uint32_t pos = atomicAdd(&lcount, 1u);     // LDS atomic — rare (~0.07%)
                if (pos < BCAP2) {
                    uint32_t idx = (uint32_t)(i * 4 + c);
                    pv[pos] = ((unsigned long long)f2sortable(fs[c]) << 32) |
                              (unsigned long long)(~idx);
                }
            }
        }
    }
    __syncthreads();
    if (tid == 0) bcount[(size_t)n * SBLK + blk] = lcount;   // uncapped (overflow check)
}

// Shared per-block prologue for rank/decode: load the 128 per-block counts,
// prefix-scan them in LDS, detect overflow. Returns total; pre[] filled.
// Cost: ~128 global loads (512 B, L2/L3-hit) + 7 Hillis-Steele steps.
__device__ __forceinline__ uint32_t build_prefix(
    const uint32_t* bcount, int n, int tid,
    uint32_t* cs, uint32_t* ps, uint32_t* pre, uint32_t* bad) {
    if (tid == 0) *bad = 0;
    __syncthreads();
    if (tid < SBLK) {
        uint32_t c = bcount[(size_t)n * SBLK + tid];
        cs[tid] = c; ps[tid] = c;
        if (c > BCAP2) atomicOr(bad, 1u);   // overflowed block -> list incomplete
    }
    __syncthreads();
    for (int off = 1; off < SBLK; off <<= 1) {   // Hillis-Steele inclusive scan
        uint32_t v = 0;
        if (tid < SBLK) { v = ps[tid]; if (tid >= off) v += ps[tid - off]; }
        __syncthreads();
        if (tid < SBLK) ps[tid] = v;
        __syncthreads();
    }
    const uint32_t total = ps[SBLK - 1];
    if (tid < SBLK) pre[tid] = ps[tid] - cs[tid];
    if (tid == 0) pre[SBLK] = total;
    __syncthreads();
    return total;
}

// ---------------- pass 2: partial ranks ----------------
// rank(t) = #{j : key_j > key_t}; keys unique -> rank == final sorted position.
// Block (grp, seg, n): partial count of its 1024 candidates (4 keys/thread in
// registers, gathered on-the-fly from priv) against one 256-key segment in LDS.
__global__ __launch_bounds__(256) void rank_partial_kernel(
    const uint32_t* __restrict__ bcount,
    const unsigned long long* __restrict__ priv,
    uint16_t* __restrict__ partial) {
    __shared__ unsigned long long s[SEGK];   // 2 KB
    __shared__ uint32_t cs[SBLK], ps[SBLK], pre[SBLK + 1], bad;
    const int n = blockIdx.z, seg = blockIdx.y, grp = blockIdx.x;
    const int tid = (int)threadIdx.x;
    const uint32_t total = build_prefix(bcount, n, tid, cs, ps, pre, &bad);
    const bool okl = (bad == 0) && (total >= TOPK) && (total <= CAP);
    if (!okl) return;                           // decode block 0 runs exact fallback
    const uint32_t cnt = total;
    if ((uint32_t)(grp * 1024) >= cnt) return;  // dead candidate range
    if ((uint32_t)(seg * SEGK) >= cnt) return;  // empty key segment
    const unsigned long long* pvb = priv + (size_t)n * SBLK * BCAP2;
    const int ks = seg * SEGK;
    for (int i = tid; i < SEGK; i += 256)
        s[i] = ((uint32_t)(ks + i) < cnt) ? gather_key(pvb, pre, ks + i) : 0ull; // pad 0 < any key
    const uint32_t t0 = (uint32_t)(grp * 1024 + tid);
    // clamp gathers for t >= cnt: those ranks are never consumed
    const uint32_t cm = cnt - 1;
    unsigned long long k0 = gather_key(pvb, pre, t0 < cm ? t0 : cm);
    unsigned long long k1 = gather_key(pvb, pre, t0 + 256 < cm ? t0 + 256 : cm);
    unsigned long long k2 = gather_key(pvb, pre, t0 + 512 < cm ? t0 + 512 : cm);
    unsigned long long k3 = gather_key(pvb, pre, t0 + 768 < cm ? t0 + 768 : cm);
    __syncthreads();
    uint32_t r0 = 0, r1 = 0, r2 = 0, r3 = 0;
    const ulonglong2* s2 = (const ulonglong2*)s;
    #pragma unroll 8
    for (int j = 0; j < SEGK / 2; ++j) {
        ulonglong2 p = s2[j];                // wave-uniform broadcast read
        r0 += (p.x > k0); r0 += (p.y > k0);
        r1 += (p.x > k1); r1 += (p.y > k1);
        r2 += (p.x > k2); r2 += (p.y > k2);
        r3 += (p.x > k3); r3 += (p.y > k3);
    }
    uint16_t* pw = partial + ((size_t)n * SEG + seg) * CAP;
    pw[t0]       = (uint16_t)r0;
    pw[t0 + 256] = (uint16_t)r1;
    pw[t0 + 512] = (uint16_t)r2;
    pw[t0 + 768] = (uint16_t)r3;
}

// ---------------- pass 3: sum partials, gather, decode, write ----------------
// Also hosts the exact fallback (block grp==0) — never taken for the fixed
// input seed (speculation holds by >10 sigma; verified absmax=0).
__global__ __launch_bounds__(256) void decode_kernel(
    const float* __restrict__ anchors, const float* __restrict__ breg,
    const float* __restrict__ obj,
    const uint32_t* __restrict__ bcount,
    unsigned long long* __restrict__ priv,      // non-const: fallback reuses it
    const uint16_t* __restrict__ partial,
    float* __restrict__ out) {
    __shared__ uint32_t cs[SBLK], ps[SBLK], pre[SBLK + 1], bad;
    __shared__ uint32_t sh[NBINS];              // 8 KB, fallback only
    __shared__ uint32_t lcnt, cutb;
    const int n = blockIdx.y;
    const int tid = (int)threadIdx.x;
    const uint32_t total = build_prefix(bcount, n, tid, cs, ps, pre, &bad);
    const bool okl = (bad == 0) && (total >= TOPK) && (total <= CAP);

    if (okl) {
        const uint32_t cnt = total;
        const uint32_t t = (uint32_t)(blockIdx.x * 256 + tid);
        if (t >= cnt) return;
        const int nseg = (int)((cnt + SEGK - 1) / SEGK);   // only written segments
        const uint16_t* pp = partial + (size_t)n * SEG * CAP;
        uint32_t rank = 0;
        for (int sg = 0; sg < nseg; ++sg) rank += pp[(size_t)sg * CAP + t];
        if (rank >= TOPK) return;
        const unsigned long long* pvb = priv + (size_t)n * SBLK * BCAP2;
        const unsigned long long mykey = gather_key(pvb, pre, t);
        const uint32_t u    = (uint32_t)(mykey >> 32);
        const uint32_t idx  = ~((uint32_t)mykey);
        const uint32_t bits = (u & 0x80000000u) ? (u ^ 0x80000000u) : ~u;
        const float score = __uint_as_float(bits);
        const float4 a = ((const float4*)anchors)[(size_t)n * A_ELEMS + idx];
        const float4 b = ((const float4*)breg)[(size_t)n * A_ELEMS + idx];
        float w  = a.z - a.x + 1.0f;
        float h  = a.w - a.y + 1.0f;
        float cx = a.x + 0.5f * w;
        float cy = a.y + 0.5f * h;
        float dw = fminf(b.z, BBOX_CLIP);
        float dh = fminf(b.w, BBOX_CLIP);
        float pcx = b.x * w + cx;
        float pcy = b.y * h + cy;
        float pw  = expf(dw) * w;
        float ph  = expf(dh) * h;
        float* row = out + ((size_t)n * TOPK + rank) * 5;
        row[0] = pcx - 0.5f * pw;
        row[1] = pcy - 0.5f * ph;
        row[2] = pcx + 0.5f * pw - 1.0f;
        row[3] = pcy + 0.5f * ph - 1.0f;
        row[4] = score;
        return;
    }

    // ---- exact fallback: single block per bad batch (~never runs) ----
    if (blockIdx.x != 0) return;
    for (int i = tid; i < NBINS; i += 256) sh[i] = 0;
    if (tid == 0) lcnt = 0;
    __syncthreads();
    const float* o = obj + (size_t)n * A_ELEMS;
    for (int i = tid; i < A_ELEMS; i += 256)
        atomicAdd(&sh[f2sortable(o[i]) >> 21], 1u);
    __syncthreads();
    if (tid == 0) {
        uint32_t cum = 0; int b;
        for (b = NBINS - 1; b > 0; --b) { cum += sh[b]; if (cum >= TOPK) break; }
        cutb = (uint32_t)b;
    }
    __syncthreads();
    const uint32_t cb = cutb;
    unsigned long long* fbn = priv + (size_t)n * SBLK * BCAP2;  // 16384 slots, safe to reuse
    for (int i = tid; i < A_ELEMS; i += 256) {
        uint32_t u = f2sortable(o[i]);
        if ((u >> 21) >= cb) {
            uint32_t pos = atomicAdd(&lcnt, 1u);
            if (pos < FBCAP)
                fbn[pos] = ((unsigned long long)u << 32) | (unsigned long long)(~(uint32_t)i);
        }
    }
    __syncthreads();
    const uint32_t cnt2 = lcnt < FBCAP ? lcnt : FBCAP;
    // brute-force rank + decode (slow but correct; never executed)
    for (uint32_t t = tid; t < cnt2; t += 256) {
        const unsigned long long myk = fbn[t];
        uint32_t rank = 0;
        for (uint32_t j = 0; j < cnt2; ++j) rank += (fbn[j] > myk);
        if (rank >= TOPK) continue;
        const uint32_t u    = (uint32_t)(myk >> 32);
        const uint32_t idx  = ~((uint32_t)myk);
        const uint32_t bits = (u & 0x80000000u) ? (u ^ 0x80000000u) : ~u;
        const float score = __uint_as_float(bits);
        const float4 a = ((const float4*)anchors)[(size_t)n * A_ELEMS + idx];
        const float4 b = ((const float4*)breg)[(size_t)n * A_ELEMS + idx];
        float w  = a.z - a.x + 1.0f;
        float h  = a.w - a.y + 1.0f;
        float cx = a.x + 0.5f * w;
        float cy = a.y + 0.5f * h;
        float dw = fminf(b.z, BBOX_CLIP);
        float dh = fminf(b.w, BBOX_CLIP);
        float pcx = b.x * w + cx;
        float pcy = b.y * h + cy;
        float pw  = expf(dw) * w;
        float ph  = expf(dh) * h;
        float* row = out + ((size_t)n * TOPK + rank) * 5;
        row[0] = pcx - 0.5f * pw;
        row[1] = pcy - 0.5f * ph;
        row[2] = pcx + 0.5f * pw - 1.0f;
        row[3] = pcy + 0.5f * ph - 1.0f;
        row[4] = score;
    }
}

extern "C" void kernel_launch(void* const* d_in, const int* in_sizes, int n_in,
                              void* d_out, int out_size, void* d_ws, size_t ws_size,
                              hipStream_t stream) {
    const float* anchors    = (const float*)d_in[0];  // [8,500000,4]
    const float* objectness = (const float*)d_in[1];  // [8,500000,1]
    const float* breg       = (const float*)d_in[2];  // [8,500000,4]
    float* out = (float*)d_out;                        // [8,2000,5]

    // Workspace layout (every region written-before-read each call):
    //   [0,       4096)     bcount   uint32[8][128]
    //   [4096,    1052672)  priv     uint64[8][128][128]   (also fallback area)
    //   [1052672, 2101248)  partial  uint16[8][16][4096]
    uint8_t* ws = (uint8_t*)d_ws;
    uint32_t* bcount         = (uint32_t*)ws;
    unsigned long long* priv = (unsigned long long*)(ws + 4096);
    uint16_t* partial        = (uint16_t*)(ws + 1052672);

    dim3 g1(SBLK, N_BATCH);
    scan_kernel<<<g1, 256, 0, stream>>>(objectness, bcount, priv);
    dim3 g2(GRP, SEG, N_BATCH);
    rank_partial_kernel<<<g2, 256, 0, stream>>>(bcount, priv, partial);
    dim3 g3(CAP / 256, N_BATCH);
    decode_kernel<<<g3, 256, 0, stream>>>(anchors, breg, objectness, bcount, priv,
                                          partial, out);
}